// Round 7
// baseline (183.638 us; speedup 1.0000x reference)
//
#include <hip/hip_runtime.h>

#define B_ 4
#define S_ 2048
#define E_ 1024

typedef __attribute__((ext_vector_type(8))) short short8;
typedef __attribute__((ext_vector_type(4))) float f32x4;

__device__ __forceinline__ unsigned short f2bu(float f) {
  unsigned u = __builtin_bit_cast(unsigned, f);
  u = (u + 0x7FFFu + ((u >> 16) & 1u)) >> 16;
  return (unsigned short)u;
}

__device__ __forceinline__ void gload_lds16(const void* g, void* l) {
  __builtin_amdgcn_global_load_lds(
      (const __attribute__((address_space(1))) void*)g,
      (__attribute__((address_space(3))) void*)l, 16, 0, 0);
}

// ---------------- fp32 -> bf16 convert ----------------
__global__ __launch_bounds__(256) void cvt_f32_bf16(
    const float* __restrict__ in, unsigned short* __restrict__ out, int n) {
  int i = blockIdx.x * 256 + threadIdx.x;
  if (i * 4 >= n) return;
  float4 v = ((const float4*)in)[i];
  ushort4 o;
  o.x = f2bu(v.x); o.y = f2bu(v.y); o.z = f2bu(v.z); o.w = f2bu(v.w);
  ((ushort4*)out)[i] = o;
}

__global__ __launch_bounds__(256) void cvt_w3(
    const float* __restrict__ w0, const float* __restrict__ w1,
    const float* __restrict__ w2, unsigned short* __restrict__ out, int n) {
  int z = blockIdx.z;
  const float* in = (z == 0) ? w0 : (z == 1) ? w1 : w2;
  int i = blockIdx.x * 256 + threadIdx.x;
  if (i * 4 >= n) return;
  float4 v = ((const float4*)in)[i];
  ushort4 o;
  o.x = f2bu(v.x); o.y = f2bu(v.y); o.z = f2bu(v.z); o.w = f2bu(v.w);
  ((ushort4*)(out + (long)z * n))[i] = o;
}

// ================= qkv256: m201-geometry 8-phase QKV GEMM =================
// C[8192][3072] = xb * [Wq;Wk;Wv]^T + bias. BM=BN=256, BK=64, 512 thr
// (8 waves 2Mx4N, wave tile 128x64). LDS 128KB: A[2dbuf][256][64],
// B[2dbuf][256][64], XOR-swizzled reads (byte ^= (row&7)<<4), linear
// global_load_lds dest + inverse-swizzled global source (rule #21).
// 4 phases/K-tile (quadrants mh x nh, 16 MFMA each).
// Read-completion ledger (cross-wave, via phase exit barriers):
//   B tile-t reads done after ph2 BAR_OUT  -> stage B(t+2) x4 in ph3
//   A tile-t reads done after ph3 BAR_OUT  -> stage A(t+2) x4 in ph4
// (Round-6 bug: A-h0 staged in ph2 raced wm=0 waves' ph3 reads of rows
//  64..127. Staging halves are block halves; readers are wave-tile halves.)
// Boundary: vmcnt(8) in ph4 after A issues (8 in flight = tile t+2's).
__global__ __launch_bounds__(512, 2) void qkv256(
    const unsigned short* __restrict__ A, const unsigned short* __restrict__ W,
    const float* __restrict__ bq, const float* __restrict__ bk,
    const float* __restrict__ bv,
    unsigned short* __restrict__ Qo, unsigned short* __restrict__ Ko,
    unsigned short* __restrict__ Vt) {
  extern __shared__ char smem[];
  constexpr int NT = 16;  // K=1024 / BK=64
  int tid = threadIdx.x;
  int l = tid & 63, w = tid >> 6;
  int wm = w >> 2, wn = w & 3;
  int bid = blockIdx.y * 12 + blockIdx.x;       // 384 blocks, 384%8==0
  int swz = (bid & 7) * 48 + (bid >> 3);        // XCD-bijective swizzle
  int tm = swz / 12, tn = swz % 12;

  // inverse-swizzled global source column (elements)
  int scol = 8 * ((l & 7) ^ ((l >> 3) & 7));
  const unsigned short* Ag = A + (long)tm * 256 * 1024 + scol;
  const unsigned short* Bg = W + (long)tn * 256 * 1024 + scol;

#define STG_A(tt, h, q)                                                  \
  gload_lds16(Ag + (long)((h) * 128 + (w * 2 + (q)) * 8 + (l >> 3)) * 1024 \
                  + (tt) * 64,                                           \
              smem + ((tt) & 1) * 32768 + (h) * 16384 + (w * 2 + (q)) * 1024)
#define STG_B(tt, h, q)                                                  \
  gload_lds16(Bg + (long)((h) * 128 + (w * 2 + (q)) * 8 + (l >> 3)) * 1024 \
                  + (tt) * 64,                                           \
              smem + 65536 + ((tt) & 1) * 32768 + (h) * 16384 + (w * 2 + (q)) * 1024)

  // swizzled LDS read cols (bytes within 128B row)
  int xorc = (l & 7) << 4;
  int c0 = ((l >> 4) * 16) ^ xorc;       // kk=0
  int c1 = (64 + (l >> 4) * 16) ^ xorc;  // kk=1
  int arow = (wm * 128 + (l & 15)) * 128;
  int brow = (wn * 64 + (l & 15)) * 128;

  f32x4 acc[8][4] = {};
  short8 a[4][2], b[2][2][2];

  // prologue: tiles 0,1
  STG_A(0, 0, 0); STG_A(0, 0, 1); STG_B(0, 0, 0); STG_B(0, 0, 1);
  STG_B(0, 1, 0); STG_B(0, 1, 1); STG_A(0, 1, 0); STG_A(0, 1, 1);
  STG_A(1, 0, 0); STG_A(1, 0, 1); STG_B(1, 0, 0); STG_B(1, 0, 1);
  STG_B(1, 1, 0); STG_B(1, 1, 1); STG_A(1, 1, 0); STG_A(1, 1, 1);
  asm volatile("s_waitcnt vmcnt(8)" ::: "memory");
  __builtin_amdgcn_s_barrier();

#define BAR_IN                                             \
  asm volatile("" ::: "memory");                           \
  __builtin_amdgcn_s_barrier();                            \
  asm volatile("s_waitcnt lgkmcnt(0)" ::: "memory");       \
  __builtin_amdgcn_sched_barrier(0);                       \
  __builtin_amdgcn_s_setprio(1);
#define BAR_OUT                                            \
  __builtin_amdgcn_s_setprio(0);                           \
  __builtin_amdgcn_sched_barrier(0);                       \
  asm volatile("" ::: "memory");                           \
  __builtin_amdgcn_s_barrier();
#define MFMA_Q(MH, NH)                                                    \
  _Pragma("unroll")                                                       \
  for (int mf = 0; mf < 4; mf++) {                                        \
    _Pragma("unroll")                                                     \
    for (int nf = 0; nf < 2; nf++) {                                      \
      acc[(MH) * 4 + mf][(NH) * 2 + nf] =                                 \
          __builtin_amdgcn_mfma_f32_16x16x32_bf16(                        \
              a[mf][0], b[NH][nf][0], acc[(MH) * 4 + mf][(NH) * 2 + nf],  \
              0, 0, 0);                                                   \
      acc[(MH) * 4 + mf][(NH) * 2 + nf] =                                 \
          __builtin_amdgcn_mfma_f32_16x16x32_bf16(                        \
              a[mf][1], b[NH][nf][1], acc[(MH) * 4 + mf][(NH) * 2 + nf],  \
              0, 0, 0);                                                   \
    }                                                                     \
  }

  for (int t = 0; t < NT; ++t) {
    const char* Ad = smem + (t & 1) * 32768;
    const char* Bd = smem + 65536 + (t & 1) * 32768;

    // ph1: read A-mh0 (8) + B-nh0 (4); compute (0,0)
#pragma unroll
    for (int mf = 0; mf < 4; mf++) {
      a[mf][0] = *(const short8*)(Ad + arow + mf * 2048 + c0);
      a[mf][1] = *(const short8*)(Ad + arow + mf * 2048 + c1);
    }
#pragma unroll
    for (int nf = 0; nf < 2; nf++) {
      b[0][nf][0] = *(const short8*)(Bd + brow + nf * 2048 + c0);
      b[0][nf][1] = *(const short8*)(Bd + brow + nf * 2048 + c1);
    }
    BAR_IN
    MFMA_Q(0, 0)
    BAR_OUT

    // ph2: read B-nh1 (4); compute (0,1)   [no staging: A rows 64..127
    //  of this buffer are still unread by wm=0 waves until ph3]
#pragma unroll
    for (int nf = 0; nf < 2; nf++) {
      b[1][nf][0] = *(const short8*)(Bd + brow + 4096 + nf * 2048 + c0);
      b[1][nf][1] = *(const short8*)(Bd + brow + 4096 + nf * 2048 + c1);
    }
    BAR_IN
    MFMA_Q(0, 1)
    BAR_OUT

    // ph3: read A-mh1 (8); stage B(t+2) x4 (B reads done at ph2 exit);
    //      compute (1,0)
#pragma unroll
    for (int mf = 0; mf < 4; mf++) {
      a[mf][0] = *(const short8*)(Ad + arow + 8192 + mf * 2048 + c0);
      a[mf][1] = *(const short8*)(Ad + arow + 8192 + mf * 2048 + c1);
    }
    if (t + 2 < NT) { STG_B(t + 2, 0, 0); STG_B(t + 2, 0, 1);
                      STG_B(t + 2, 1, 0); STG_B(t + 2, 1, 1); }
    BAR_IN
    MFMA_Q(1, 0)
    BAR_OUT

    // ph4: stage A(t+2) x4 (A reads done at ph3 exit); boundary vmcnt
    //      for tile t+1; compute (1,1)
    if (t + 2 < NT) { STG_A(t + 2, 0, 0); STG_A(t + 2, 0, 1);
                      STG_A(t + 2, 1, 0); STG_A(t + 2, 1, 1); }
    if (t < NT - 2)       asm volatile("s_waitcnt vmcnt(8)" ::: "memory");
    else if (t == NT - 2) asm volatile("s_waitcnt vmcnt(0)" ::: "memory");
    BAR_IN
    MFMA_Q(1, 1)
    BAR_OUT
  }

  // epilogue: D col=lane&15, row=(lane>>4)*4+t4  [m89-verified]
  int rh = l >> 4, cl = l & 15;
  int seg = tn >> 2;  // 0=Q 1=K 2=V (block-uniform)
  const float* bias = (seg == 0) ? bq : (seg == 1) ? bk : bv;
  long rowbase = (long)tm * 256 + wm * 128 + rh * 4;
  int cmbase = (tn & 3) * 256 + wn * 64 + cl;
#pragma unroll
  for (int nf = 0; nf < 4; nf++) {
    int cm = cmbase + nf * 16;
    float bv_ = bias[cm];
#pragma unroll
    for (int mf = 0; mf < 8; mf++) {
      long r0 = rowbase + mf * 16;
      f32x4 v = acc[mf][nf];
      if (seg < 2) {
        unsigned short* Ch = seg ? Ko : Qo;
#pragma unroll
        for (int t4 = 0; t4 < 4; t4++)
          Ch[(r0 + t4) * (long)E_ + cm] = f2bu(v[t4] + bv_);
      } else {
        ushort4 pk;
        pk.x = f2bu(v[0] + bv_);
        pk.y = f2bu(v[1] + bv_);
        pk.z = f2bu(v[2] + bv_);
        pk.w = f2bu(v[3] + bv_);
        *(ushort4*)(Vt + (long)cm * (B_ * S_) + r0) = pk;
      }
    }
  }
#undef STG_A
#undef STG_B
#undef BAR_IN
#undef BAR_OUT
#undef MFMA_Q
}

// ---------------- B^T GEMM, m97 structure (scores / PV) ----------------
// MODE 1 (SCORES+EXP): lower-tri linear grid (136,1,4); epilogue writes
//                 P' = exp(s/32) bf16 (c<=r else 0) to C0 (lda S_).
// MODE 2 (PV+NORM): A=P' bf16 (lda S_), B=Vt(1024x8192), Keff=(bm+1)*128.
//                 Extra all-ones B-frag accumulates row denom; epilogue divides.
template<int MODE>
__global__ __launch_bounds__(256, 3) void gemm_bt(
    const unsigned short* __restrict__ A, long sAz, int lda,
    const unsigned short* __restrict__ B, long sBz, int ldb,
    void* __restrict__ C0, long sCz, int ldc, int K, float scale) {
  constexpr int BM = 128, BN = 128, BK = 64;
  __shared__ unsigned short lA[BM * BK];
  __shared__ unsigned short lB[BN * BK];
  int bm, bn;
  int bz = blockIdx.z;
  if constexpr (MODE == 1) {
    int t = blockIdx.x;  // 0..135 lower-tri linear
    bm = (int)((sqrtf(8.f * t + 1.f) - 1.f) * 0.5f);
    while ((bm + 1) * (bm + 2) / 2 <= t) bm++;
    while (bm * (bm + 1) / 2 > t) bm--;
    bn = t - bm * (bm + 1) / 2;
  } else {
    bm = blockIdx.y; bn = blockIdx.x;
  }
  const unsigned short* Ab = A + (long)bz * sAz + (long)bm * BM * lda;
  const unsigned short* Bb = B + (long)bz * sBz + (long)bn * BN * ldb;
  int Keff = (MODE == 2) ? min(K, (bm + 1) * BM) : K;

  int tid = threadIdx.x;
  int l = tid & 63, w = tid >> 6;
  int wm = w >> 1, wn = w & 1;

  int srow = l >> 3;
  int schunk = (l & 7) * 8;
  const unsigned short* ga[4];
  const unsigned short* gb[4];
  unsigned short* lad[4];
  unsigned short* lbd[4];
#pragma unroll
  for (int i = 0; i < 4; i++) {
    int seg = i * 4 + w;
    int row = seg * 8 + srow;
    ga[i] = Ab + (long)row * lda + schunk;
    gb[i] = Bb + (long)row * ldb + schunk;
    lad[i] = &lA[seg * 512];
    lbd[i] = &lB[seg * 512];
  }
  int aoff[4], boff[4];
#pragma unroll
  for (int i = 0; i < 4; i++) {
    aoff[i] = (wm * 64 + i * 16 + (l & 15)) * BK + (l >> 4) * 8;
    boff[i] = (wn * 64 + i * 16 + (l & 15)) * BK + (l >> 4) * 8;
  }

  f32x4 acc[4][4] = {};
  f32x4 accd[4] = {};
  short8 ones;
#pragma unroll
  for (int z = 0; z < 8; z++) ones[z] = (short)0x3F80;

  for (int k0 = 0; k0 < Keff; k0 += BK) {
    __syncthreads();
#pragma unroll
    for (int i = 0; i < 4; i++) {
      gload_lds16(ga[i], lad[i]);
      gload_lds16(gb[i], lbd[i]);
    }
#pragma unroll
    for (int i = 0; i < 4; i++) { ga[i] += BK; gb[i] += BK; }
    __syncthreads();
#pragma unroll
    for (int kk = 0; kk < 2; kk++) {
      short8 af[4], bf[4];
#pragma unroll
      for (int i = 0; i < 4; i++) af[i] = *(const short8*)&lA[aoff[i] + kk * 32];
#pragma unroll
      for (int j = 0; j < 4; j++) bf[j] = *(const short8*)&lB[boff[j] + kk * 32];
#pragma unroll
      for (int i = 0; i < 4; i++)
#pragma unroll
        for (int j = 0; j < 4; j++)
          acc[i][j] = __builtin_amdgcn_mfma_f32_16x16x32_bf16(af[i], bf[j], acc[i][j], 0, 0, 0);
      if constexpr (MODE == 2) {
#pragma unroll
        for (int i = 0; i < 4; i++)
          accd[i] = __builtin_amdgcn_mfma_f32_16x16x32_bf16(af[i], ones, accd[i], 0, 0, 0);
      }
    }
  }

  int rh = l >> 4, cl = l & 15;
  long rowbase = (long)bm * BM + wm * 64 + rh * 4;
  int colbase = bn * BN + wn * 64 + cl;

  if constexpr (MODE == 1) {
    unsigned short* Ph = (unsigned short*)C0 + (long)bz * sCz;
#pragma unroll
    for (int j = 0; j < 4; j++) {
      int c = colbase + j * 16;
#pragma unroll
      for (int i = 0; i < 4; i++) {
        int r0 = (int)rowbase + i * 16;
        f32x4 v = acc[i][j];
#pragma unroll
        for (int t = 0; t < 4; t++) {
          int r = r0 + t;
          float p = (c <= r) ? __expf(v[t] * scale) : 0.f;
          Ph[(long)r * ldc + c] = f2bu(p);
        }
      }
    }
  } else {
    float* Cf = (float*)C0 + (long)bz * sCz;
#pragma unroll
    for (int j = 0; j < 4; j++) {
      int c = colbase + j * 16;
#pragma unroll
      for (int i = 0; i < 4; i++) {
        long r0 = rowbase + i * 16;
        f32x4 v = acc[i][j];
        f32x4 d = accd[i];
#pragma unroll
        for (int t = 0; t < 4; t++)
          Cf[(r0 + t) * (long)ldc + c] = v[t] / d[t];
      }
    }
  }
}

// ---------------- host ----------------
extern "C" void kernel_launch(void* const* d_in, const int* in_sizes, int n_in,
                              void* d_out, int out_size, void* d_ws, size_t ws_size,
                              hipStream_t stream) {
  const float* x  = (const float*)d_in[0];
  const float* Wq = (const float*)d_in[2];
  const float* bq = (const float*)d_in[3];
  const float* Wk = (const float*)d_in[4];
  const float* bk = (const float*)d_in[5];
  const float* Wv = (const float*)d_in[6];
  const float* bv = (const float*)d_in[7];
  float* out = (float*)d_out;

  const long NX = (long)B_ * S_ * E_;  // 8388608
  const long NW = (long)E_ * E_;       // 1048576
  unsigned short* xb  = (unsigned short*)d_ws;
  unsigned short* wqb = xb + NX;       // [3072][1024] contiguous (q,k,v)
  unsigned short* Qb  = wqb + 3 * NW;
  unsigned short* Kb  = Qb + NX;
  unsigned short* Vtb = Kb + NX;       // layout [E][B*S]
  unsigned short* Pb  = Vtb + NX;      // [B][S][S] bf16 unnormalized exp-scores

  static int smem_set = 0;
  if (!smem_set) {
    hipFuncSetAttribute((const void*)qkv256,
                        hipFuncAttributeMaxDynamicSharedMemorySize, 131072);
    smem_set = 1;
  }

  cvt_f32_bf16<<<8192, 256, 0, stream>>>(x, xb, (int)NX);
  cvt_w3<<<dim3(1024, 1, 3), 256, 0, stream>>>(Wq, Wk, Wv, wqb, (int)NW);

  // fused QKV, m201-geometry deep pipeline
  qkv256<<<dim3(12, 32), 512, 131072, stream>>>(
      xb, wqb, bq, bk, bv, Qb, Kb, Vtb);

  // P' = exp(Q K^T / 32) (causal, bf16), lower-tri linear grid
  gemm_bt<1><<<dim3(136, 1, 4), 256, 0, stream>>>(
      Qb, (long)S_ * E_, E_, Kb, (long)S_ * E_, E_,
      Pb, (long)S_ * S_, S_, E_, 0.03125f);

  // out = (P' V) / rowsum(P') : A = P', B = Vt (N=E, K=S), denom via ones-MFMA
  gemm_bt<2><<<dim3(8, 16, 4), 256, 0, stream>>>(
      Pb, (long)S_ * S_, S_,
      Vtb, (long)S_, B_ * S_,
      out, (long)S_ * E_, E_, S_, 1.f);
}